// Round 2
// baseline (5722.882 us; speedup 1.0000x reference)
//
#include <hip/hip_runtime.h>
#include <math.h>

#define BB 16384
#define P 20
#define SPB 16
#define NT 512

// C (edge counts) and M (normalized agg matrices) live in device globals:
// no workspace, no hipMemsetAsync — zeroed by a kernel on-stream each call.
__device__ unsigned int g_C[3][P * P];
__device__ float g_M[3][P * P];

__global__ void zero_C_kernel() {
    g_C[blockIdx.x][threadIdx.x] = 0u;
}

// ---------------- device helpers (all LDS strides multiples of 4) ----------

template<int DIN, int SH>
__device__ inline void stage_x(const float* __restrict__ g, float* hs, int t) {
    const float4* src = (const float4*)g;
    for (int i = t; i < P * DIN / 4; i += NT) {
        float4 v = src[i];
        int r = (i * 4) / DIN, c = (i * 4) % DIN;
        *(float4*)(hs + r * SH + c) = v;
    }
}

// zs[v][d] = sum_u Ms[v,u] * hs[u][d]
template<int DIN, int SH, int SZ>
__device__ inline void agg(const float* Ms, const float* hs, float* zs, int t) {
    for (int i = t; i < P * DIN; i += NT) {
        int v = i / DIN, d = i % DIN;
        float acc = 0.f;
#pragma unroll
        for (int u = 0; u < P; ++u) acc += Ms[v * P + u] * hs[u * SH + d];
        zs[v * SZ + d] = acc;
    }
}

// hs[v][j] = relu(dot(zs[v][:DIN], W[j][:DIN]) + b[j]); VS threads share one j
template<int DIN, int DOUT, int VS, int SZ, int SH>
__device__ inline void dense_relu(const float* zs, const float* __restrict__ W,
                                  const float* __restrict__ bias, float* hs, int t) {
    constexpr int NV = P / VS;
    for (int jt = t; jt < DOUT * VS; jt += NT) {
        const int j = jt % DOUT;
        const int v0 = (jt / DOUT) * NV;
        float acc[NV];
#pragma unroll
        for (int v = 0; v < NV; ++v) acc[v] = 0.f;
        const float4* wrow = (const float4*)(W + (size_t)j * DIN);
        for (int d4 = 0; d4 < DIN / 4; ++d4) {
            float4 w = wrow[d4];
#pragma unroll
            for (int v = 0; v < NV; ++v) {
                float4 z = *(const float4*)(zs + (v0 + v) * SZ + d4 * 4);
                acc[v] += z.x * w.x + z.y * w.y + z.z * w.z + z.w * w.w;
            }
        }
        const float bj = bias[j];
#pragma unroll
        for (int v = 0; v < NV; ++v)
            hs[(v0 + v) * SH + j] = fmaxf(acc[v] + bj, 0.f);
    }
}

// d2 = sq+sq-2dot (diag exact 0), top-6-smallest per row (ties -> lowest idx),
// drop first (self), hist[nbr*P+src] += 1.   Must be called by ALL NT threads.
template<int DIN, int SH>
__device__ inline void knn_accum(const float* hbuf, float* d2s,
                                 unsigned int* hist, int t) {
    const int p = t / P, q = t % P;
    float dotv = 0.f;
    if (t < P * P) {
        for (int d = 0; d < DIN; d += 4) {
            float4 a = *(const float4*)(hbuf + p * SH + d);
            float4 b = *(const float4*)(hbuf + q * SH + d);
            dotv += a.x * b.x + a.y * b.y + a.z * b.z + a.w * b.w;
        }
        d2s[t] = dotv;   // dots; diag = sq
    }
    __syncthreads();
    float dv = 0.f;
    if (t < P * P && p != q)
        dv = d2s[p * P + p] + d2s[q * P + q] - 2.f * dotv;
    __syncthreads();
    if (t < P * P) d2s[t] = dv;  // distances; diag exact 0
    __syncthreads();
    if (t < P) {
        float pv = -3.0e38f; int pi = -1;
        for (int it = 0; it < 6; ++it) {
            float best = 3.0e38f; int bq = 0;
            for (int u = 0; u < P; ++u) {
                float vu = d2s[t * P + u];
                bool cand = (vu > pv) || (vu == pv && u > pi);
                if (cand && vu < best) { best = vu; bq = u; }
            }
            if (it > 0) atomicAdd(&hist[bq * P + t], 1u);
            pv = best; pi = bq;
        }
    }
}

// ---------------- kernels ----------------

// kNN on raw x -> g_C[0]
__global__ __launch_bounds__(NT)
void knn1_kernel(const float* __restrict__ x) {
    __shared__ __align__(16) float xs[P * 132];
    __shared__ float d2s[P * P];
    __shared__ unsigned int hist[P * P];
    const int t = threadIdx.x;
    if (t < P * P) hist[t] = 0;
    for (int si = 0; si < SPB; ++si) {
        const size_t s = (size_t)blockIdx.x * SPB + si;
        __syncthreads();
        stage_x<128, 132>(x + s * P * 128, xs, t);
        __syncthreads();
        knn_accum<128, 132>(xs, d2s, hist, t);
    }
    __syncthreads();
    if (t < P * P && hist[t]) atomicAdd(&g_C[0][t], hist[t]);
}

// g_C[L] -> g_M[L]
template<int L>
__global__ __launch_bounds__(NT)
void mat_kernel() {
    __shared__ float Cs[P * P];
    __shared__ float dinv[P];
    const int t = threadIdx.x;
    if (t < P * P) Cs[t] = (float)g_C[L][t];
    __syncthreads();
    if (t < P) {
        float deg = 1.f;
        for (int u = 0; u < P; ++u) deg += Cs[t * P + u];
        dinv[t] = 1.f / sqrtf(deg);
    }
    __syncthreads();
    if (t < P * P) {
        int v = t / P, u = t % P;
        float m = dinv[v] * Cs[t] * dinv[u];
        if (v == u) m += dinv[v] * dinv[v];
        g_M[L][t] = m;
    }
}

// h1 = relu((M1 x) W1^T + b1); kNN(h1) -> g_C[1]
__global__ __launch_bounds__(NT)
void fused_l1_knn2(const float* __restrict__ x, const float* __restrict__ W1,
                   const float* __restrict__ b1) {
    __shared__ __align__(16) float xs[P * 132];
    __shared__ __align__(16) float zs[P * 132];
    __shared__ __align__(16) float h1s[P * 300];
    __shared__ float M0s[P * P];
    __shared__ float d2s[P * P];
    __shared__ unsigned int hist[P * P];
    const int t = threadIdx.x;
    if (t < P * P) { M0s[t] = g_M[0][t]; hist[t] = 0; }
    for (int si = 0; si < SPB; ++si) {
        const size_t s = (size_t)blockIdx.x * SPB + si;
        __syncthreads();
        stage_x<128, 132>(x + s * P * 128, xs, t);
        __syncthreads();
        agg<128, 132, 132>(M0s, xs, zs, t);
        __syncthreads();
        dense_relu<128, 300, 2, 132, 300>(zs, W1, b1, h1s, t);
        __syncthreads();
        knn_accum<300, 300>(h1s, d2s, hist, t);
    }
    __syncthreads();
    if (t < P * P && hist[t]) atomicAdd(&g_C[1][t], hist[t]);
}

// recompute h1; h2 = relu((M2 h1) W2^T + b2); kNN(h2) -> g_C[2]
__global__ __launch_bounds__(NT)
void fused_l2_knn3(const float* __restrict__ x, const float* __restrict__ W1,
                   const float* __restrict__ b1, const float* __restrict__ W2,
                   const float* __restrict__ b2) {
    __shared__ __align__(16) float xs[P * 132];
    __shared__ __align__(16) float zs[P * 300];
    __shared__ __align__(16) float h1s[P * 300];
    __shared__ __align__(16) float h2s[P * 100];
    __shared__ float M0s[P * P];
    __shared__ float M1s[P * P];
    __shared__ float d2s[P * P];
    __shared__ unsigned int hist[P * P];
    const int t = threadIdx.x;
    if (t < P * P) { M0s[t] = g_M[0][t]; M1s[t] = g_M[1][t]; hist[t] = 0; }
    for (int si = 0; si < SPB; ++si) {
        const size_t s = (size_t)blockIdx.x * SPB + si;
        __syncthreads();
        stage_x<128, 132>(x + s * P * 128, xs, t);
        __syncthreads();
        agg<128, 132, 300>(M0s, xs, zs, t);
        __syncthreads();
        dense_relu<128, 300, 2, 300, 300>(zs, W1, b1, h1s, t);
        __syncthreads();
        agg<300, 300, 300>(M1s, h1s, zs, t);
        __syncthreads();
        dense_relu<300, 100, 4, 300, 100>(zs, W2, b2, h2s, t);
        __syncthreads();
        knn_accum<100, 100>(h2s, d2s, hist, t);
    }
    __syncthreads();
    if (t < P * P && hist[t]) atomicAdd(&g_C[2][t], hist[t]);
}

// recompute h1,h2; h3; h4 = relu(W4 h3 + b4); logits; softmax -> out
__global__ __launch_bounds__(NT)
void fused_tail(const float* __restrict__ x, const float* __restrict__ W1,
                const float* __restrict__ b1, const float* __restrict__ W2,
                const float* __restrict__ b2, const float* __restrict__ W3,
                const float* __restrict__ b3, const float* __restrict__ W4,
                const float* __restrict__ b4, const float* __restrict__ W5,
                const float* __restrict__ b5, float* __restrict__ out) {
    __shared__ __align__(16) float xs[P * 132];
    __shared__ __align__(16) float zs[P * 300];
    __shared__ __align__(16) float h1s[P * 300];
    __shared__ __align__(16) float h2s[P * 100];
    __shared__ __align__(16) float h3s[P * 50];   // flat == h.reshape(B,1000) layout
    __shared__ float M0s[P * P];
    __shared__ float M1s[P * P];
    __shared__ float M2s[P * P];
    __shared__ float part[500];
    __shared__ float h4s[100];
    __shared__ float lg[3];
    const int t = threadIdx.x;
    if (t < P * P) { M0s[t] = g_M[0][t]; M1s[t] = g_M[1][t]; M2s[t] = g_M[2][t]; }
    for (int si = 0; si < SPB; ++si) {
        const size_t s = (size_t)blockIdx.x * SPB + si;
        __syncthreads();
        stage_x<128, 132>(x + s * P * 128, xs, t);
        __syncthreads();
        agg<128, 132, 300>(M0s, xs, zs, t);
        __syncthreads();
        dense_relu<128, 300, 2, 300, 300>(zs, W1, b1, h1s, t);
        __syncthreads();
        agg<300, 300, 300>(M1s, h1s, zs, t);
        __syncthreads();
        dense_relu<300, 100, 4, 300, 100>(zs, W2, b2, h2s, t);
        __syncthreads();
        agg<100, 100, 300>(M2s, h2s, zs, t);
        __syncthreads();
        dense_relu<100, 50, 10, 300, 50>(zs, W3, b3, h3s, t);
        __syncthreads();
        // h4: 100 outputs, K=1000 split into 5 chunks of 200
        if (t < 500) {
            const int j = t / 5, kc = t % 5;
            float acc = 0.f;
            const float4* wrow = (const float4*)(W4 + (size_t)j * 1000 + kc * 200);
            const float4* hrow = (const float4*)(h3s + kc * 200);
            for (int k4 = 0; k4 < 50; ++k4) {
                float4 w = wrow[k4];
                float4 h = hrow[k4];
                acc += h.x * w.x + h.y * w.y + h.z * w.z + h.w * w.w;
            }
            part[t] = acc;
        }
        __syncthreads();
        if (t < 100) {
            float v = part[t * 5] + part[t * 5 + 1] + part[t * 5 + 2]
                    + part[t * 5 + 3] + part[t * 5 + 4] + b4[t];
            h4s[t] = fmaxf(v, 0.f);
        }
        __syncthreads();
        if (t < 3) {
            float acc = b5[t];
            for (int k = 0; k < 100; ++k) acc += h4s[k] * W5[t * 100 + k];
            lg[t] = acc;
        }
        __syncthreads();
        if (t < 3) {
            float l0 = lg[0], l1 = lg[1], l2 = lg[2];
            float m = fmaxf(l0, fmaxf(l1, l2));
            float e0 = expf(l0 - m), e1 = expf(l1 - m), e2 = expf(l2 - m);
            float inv = 1.f / (e0 + e1 + e2);
            float e = (t == 0 ? e0 : (t == 1 ? e1 : e2));
            out[s * 3 + t] = e * inv;
        }
    }
}

extern "C" void kernel_launch(void* const* d_in, const int* in_sizes, int n_in,
                              void* d_out, int out_size, void* d_ws, size_t ws_size,
                              hipStream_t stream) {
    const float* x  = (const float*)d_in[0];
    const float* W1 = (const float*)d_in[1];
    const float* b1 = (const float*)d_in[2];
    const float* W2 = (const float*)d_in[3];
    const float* b2 = (const float*)d_in[4];
    const float* W3 = (const float*)d_in[5];
    const float* b3 = (const float*)d_in[6];
    const float* W4 = (const float*)d_in[7];
    const float* b4 = (const float*)d_in[8];
    const float* W5 = (const float*)d_in[9];
    const float* b5 = (const float*)d_in[10];
    float* out = (float*)d_out;

    zero_C_kernel<<<3, P * P, 0, stream>>>();
    knn1_kernel<<<BB / SPB, NT, 0, stream>>>(x);
    mat_kernel<0><<<1, NT, 0, stream>>>();
    fused_l1_knn2<<<BB / SPB, NT, 0, stream>>>(x, W1, b1);
    mat_kernel<1><<<1, NT, 0, stream>>>();
    fused_l2_knn3<<<BB / SPB, NT, 0, stream>>>(x, W1, b1, W2, b2);
    mat_kernel<2><<<1, NT, 0, stream>>>();
    fused_tail<<<BB / SPB, NT, 0, stream>>>(x, W1, b1, W2, b2, W3, b3,
                                            W4, b4, W5, b5, out);
}

// Round 3
// 4974.520 us; speedup vs baseline: 1.1504x; 1.1504x over previous
//
#include <hip/hip_runtime.h>
#include <math.h>

#define BB 16384
#define P 20
#define SPB 16
#define NT 512

// Static device buffers: no workspace (round-1 ws failure), never poisoned,
// fully rewritten each call. h1: 393 MB, h2: 131 MB.
__device__ unsigned int g_C[3][P * P];
__device__ float g_h1[(size_t)BB * P * 300];
__device__ float g_h2[(size_t)BB * P * 100];

__global__ void zero_C_kernel() {
    g_C[blockIdx.x][threadIdx.x] = 0u;
}

// ---------------- device helpers ----------------

// Load sample (P x DIN, contiguous) into LDS with row stride SH (mult of 4).
template<int DIN, int SH>
__device__ inline void stage_x(const float* __restrict__ g, float* hs, int t) {
    const float4* src = (const float4*)g;
    for (int i = t; i < P * DIN / 4; i += NT) {
        float4 v = src[i];
        int r = (i * 4) / DIN, c = (i * 4) % DIN;
        *(float4*)(hs + r * SH + c) = v;
    }
}

// Store LDS (stride == D, contiguous) to global.
template<int D>
__device__ inline void store_h(float* __restrict__ g, const float* hs, int t) {
    float4* dst = (float4*)g;
    for (int i = t; i < P * D / 4; i += NT)
        dst[i] = *(const float4*)(hs + i * 4);
}

// Compute M into Ms[] from completed g_C[L]. Leaves Ms valid after return.
__device__ inline void compute_M(const unsigned int* __restrict__ Cg,
                                 float* Ms, float* dinv, int t) {
    if (t < P * P) Ms[t] = (float)Cg[t];
    __syncthreads();
    if (t < P) {
        float deg = 1.f;
        for (int u = 0; u < P; ++u) deg += Ms[t * P + u];
        dinv[t] = 1.f / sqrtf(deg);
    }
    __syncthreads();
    if (t < P * P) {
        int v = t / P, u = t % P;
        float m = dinv[v] * Ms[t] * dinv[u];
        if (v == u) m += dinv[v] * dinv[v];
        Ms[t] = m;
    }
    __syncthreads();
}

// zs[v][d] = sum_u Ms[v,u] * hs[u][d]
template<int DIN, int SH, int SZ>
__device__ inline void agg(const float* Ms, const float* hs, float* zs, int t) {
    for (int i = t; i < P * DIN; i += NT) {
        int v = i / DIN, d = i % DIN;
        float acc = 0.f;
#pragma unroll
        for (int u = 0; u < P; ++u) acc += Ms[v * P + u] * hs[u * SH + d];
        zs[v * SZ + d] = acc;
    }
}

// hs[v][j] = relu(dot(zs[v],W[j]) + b[j]).
// JB adjacent j-rows per thread (amortize LDS z reads), VS threads split the
// 20 v's. items = (DOUT/JB)*VS, sized ~500 for NT=512.
template<int DIN, int DOUT, int JB, int VS, int SZ, int SH>
__device__ inline void dense_relu(const float* zs, const float* __restrict__ W,
                                  const float* __restrict__ bias, float* hs, int t) {
    constexpr int NV = P / VS;
    constexpr int NJ = DOUT / JB;
    for (int it = t; it < NJ * VS; it += NT) {
        const int jp = it % NJ;
        const int j0 = jp * JB;
        const int v0 = (it / NJ) * NV;
        float acc[JB][NV];
#pragma unroll
        for (int jj = 0; jj < JB; ++jj)
#pragma unroll
            for (int v = 0; v < NV; ++v) acc[jj][v] = 0.f;
        for (int d4 = 0; d4 < DIN / 4; ++d4) {
            float4 w[JB];
#pragma unroll
            for (int jj = 0; jj < JB; ++jj)
                w[jj] = *(const float4*)(W + (size_t)(j0 + jj) * DIN + d4 * 4);
#pragma unroll
            for (int v = 0; v < NV; ++v) {
                float4 z = *(const float4*)(zs + (v0 + v) * SZ + d4 * 4);
#pragma unroll
                for (int jj = 0; jj < JB; ++jj)
                    acc[jj][v] += z.x * w[jj].x + z.y * w[jj].y
                                + z.z * w[jj].z + z.w * w[jj].w;
            }
        }
#pragma unroll
        for (int jj = 0; jj < JB; ++jj) {
            const float bj = bias[j0 + jj];
#pragma unroll
            for (int v = 0; v < NV; ++v)
                hs[(v0 + v) * SH + j0 + jj] = fmaxf(acc[jj][v] + bj, 0.f);
        }
    }
}

// d2 = sq+sq-2dot (diag exact 0), top-6-smallest per row (ties -> lowest idx),
// drop first (self), hist[nbr*P+src] += 1.  Call with ALL NT threads.
template<int DIN, int SH>
__device__ inline void knn_accum(const float* hbuf, float* d2s,
                                 unsigned int* hist, int t) {
    const int p = t / P, q = t % P;
    float dotv = 0.f;
    if (t < P * P) {
        for (int d = 0; d < DIN; d += 4) {
            float4 a = *(const float4*)(hbuf + p * SH + d);
            float4 b = *(const float4*)(hbuf + q * SH + d);
            dotv += a.x * b.x + a.y * b.y + a.z * b.z + a.w * b.w;
        }
        d2s[t] = dotv;   // dots; diag = sq
    }
    __syncthreads();
    float dv = 0.f;
    if (t < P * P && p != q)
        dv = d2s[p * P + p] + d2s[q * P + q] - 2.f * dotv;
    __syncthreads();
    if (t < P * P) d2s[t] = dv;  // distances; diag exact 0
    __syncthreads();
    if (t < P) {
        float pv = -3.0e38f; int pi = -1;
        for (int it = 0; it < 6; ++it) {
            float best = 3.0e38f; int bq = 0;
            for (int u = 0; u < P; ++u) {
                float vu = d2s[t * P + u];
                bool cand = (vu > pv) || (vu == pv && u > pi);
                if (cand && vu < best) { best = vu; bq = u; }
            }
            if (it > 0) atomicAdd(&hist[bq * P + t], 1u);
            pv = best; pi = bq;
        }
    }
}

// ---------------- kernels ----------------

// kNN on raw x -> g_C[0]
__global__ __launch_bounds__(NT)
void knn1_kernel(const float* __restrict__ x) {
    __shared__ __align__(16) float xs[P * 132];
    __shared__ float d2s[P * P];
    __shared__ unsigned int hist[P * P];
    const int t = threadIdx.x;
    if (t < P * P) hist[t] = 0;
    for (int si = 0; si < SPB; ++si) {
        const size_t s = (size_t)blockIdx.x * SPB + si;
        __syncthreads();
        stage_x<128, 132>(x + s * P * 128, xs, t);
        __syncthreads();
        knn_accum<128, 132>(xs, d2s, hist, t);
    }
    __syncthreads();
    if (t < P * P && hist[t]) atomicAdd(&g_C[0][t], hist[t]);
}

// M0 from C0; h1 = relu((M0 x) W1^T + b1) -> store g_h1; kNN(h1) -> g_C[1]
__global__ __launch_bounds__(NT)
void l1_kernel(const float* __restrict__ x, const float* __restrict__ W1,
               const float* __restrict__ b1) {
    __shared__ __align__(16) float xs[P * 132];
    __shared__ __align__(16) float zs[P * 132];
    __shared__ __align__(16) float h1s[P * 300];
    __shared__ float M0s[P * P];
    __shared__ float dinv[P];
    __shared__ float d2s[P * P];
    __shared__ unsigned int hist[P * P];
    const int t = threadIdx.x;
    compute_M(g_C[0], M0s, dinv, t);
    if (t < P * P) hist[t] = 0;
    for (int si = 0; si < SPB; ++si) {
        const size_t s = (size_t)blockIdx.x * SPB + si;
        __syncthreads();
        stage_x<128, 132>(x + s * P * 128, xs, t);
        __syncthreads();
        agg<128, 132, 132>(M0s, xs, zs, t);
        __syncthreads();
        dense_relu<128, 300, 3, 5, 132, 300>(zs, W1, b1, h1s, t);
        __syncthreads();
        store_h<300>(g_h1 + s * (P * 300), h1s, t);
        knn_accum<300, 300>(h1s, d2s, hist, t);
    }
    __syncthreads();
    if (t < P * P && hist[t]) atomicAdd(&g_C[1][t], hist[t]);
}

// M1 from C1; h2 = relu((M1 h1) W2^T + b2) -> store g_h2; kNN(h2) -> g_C[2]
__global__ __launch_bounds__(NT)
void l2_kernel(const float* __restrict__ W2, const float* __restrict__ b2) {
    __shared__ __align__(16) float h1s[P * 300];
    __shared__ __align__(16) float zs[P * 300];
    __shared__ __align__(16) float h2s[P * 100];
    __shared__ float M1s[P * P];
    __shared__ float dinv[P];
    __shared__ float d2s[P * P];
    __shared__ unsigned int hist[P * P];
    const int t = threadIdx.x;
    compute_M(g_C[1], M1s, dinv, t);
    if (t < P * P) hist[t] = 0;
    for (int si = 0; si < SPB; ++si) {
        const size_t s = (size_t)blockIdx.x * SPB + si;
        __syncthreads();
        stage_x<300, 300>(g_h1 + s * (P * 300), h1s, t);
        __syncthreads();
        agg<300, 300, 300>(M1s, h1s, zs, t);
        __syncthreads();
        dense_relu<300, 100, 2, 10, 300, 100>(zs, W2, b2, h2s, t);
        __syncthreads();
        store_h<100>(g_h2 + s * (P * 100), h2s, t);
        knn_accum<100, 100>(h2s, d2s, hist, t);
    }
    __syncthreads();
    if (t < P * P && hist[t]) atomicAdd(&g_C[2][t], hist[t]);
}

// M2 from C2; h3 = relu((M2 h2) W3^T + b3); h4 = relu(W4 h3 + b4);
// logits = W5 h4 + b5; softmax -> out
__global__ __launch_bounds__(NT)
void tail_kernel(const float* __restrict__ W3, const float* __restrict__ b3,
                 const float* __restrict__ W4, const float* __restrict__ b4,
                 const float* __restrict__ W5, const float* __restrict__ b5,
                 float* __restrict__ out) {
    __shared__ __align__(16) float h2s[P * 100];
    __shared__ __align__(16) float zs[P * 100];
    __shared__ __align__(16) float h3s[P * 50];   // == h.reshape(1000) layout
    __shared__ float M2s[P * P];
    __shared__ float dinv[P];
    __shared__ float part[500];
    __shared__ float h4s[100];
    __shared__ float lg[3];
    const int t = threadIdx.x;
    compute_M(g_C[2], M2s, dinv, t);
    for (int si = 0; si < SPB; ++si) {
        const size_t s = (size_t)blockIdx.x * SPB + si;
        __syncthreads();
        stage_x<100, 100>(g_h2 + s * (P * 100), h2s, t);
        __syncthreads();
        agg<100, 100, 100>(M2s, h2s, zs, t);
        __syncthreads();
        dense_relu<100, 50, 2, 20, 100, 50>(zs, W3, b3, h3s, t);
        __syncthreads();
        // h4: 100 outputs, K=1000 split into 5 chunks of 200
        if (t < 500) {
            const int j = t / 5, kc = t % 5;
            float acc = 0.f;
            const float4* wrow = (const float4*)(W4 + (size_t)j * 1000 + kc * 200);
            const float4* hrow = (const float4*)(h3s + kc * 200);
            for (int k4 = 0; k4 < 50; ++k4) {
                float4 w = wrow[k4];
                float4 h = hrow[k4];
                acc += h.x * w.x + h.y * w.y + h.z * w.z + h.w * w.w;
            }
            part[t] = acc;
        }
        __syncthreads();
        if (t < 100) {
            float v = part[t * 5] + part[t * 5 + 1] + part[t * 5 + 2]
                    + part[t * 5 + 3] + part[t * 5 + 4] + b4[t];
            h4s[t] = fmaxf(v, 0.f);
        }
        __syncthreads();
        if (t < 3) {
            float acc = b5[t];
            for (int k = 0; k < 100; ++k) acc += h4s[k] * W5[t * 100 + k];
            lg[t] = acc;
        }
        __syncthreads();
        if (t < 3) {
            float l0 = lg[0], l1 = lg[1], l2 = lg[2];
            float m = fmaxf(l0, fmaxf(l1, l2));
            float e0 = expf(l0 - m), e1 = expf(l1 - m), e2 = expf(l2 - m);
            float inv = 1.f / (e0 + e1 + e2);
            float e = (t == 0 ? e0 : (t == 1 ? e1 : e2));
            out[s * 3 + t] = e * inv;
        }
    }
}

extern "C" void kernel_launch(void* const* d_in, const int* in_sizes, int n_in,
                              void* d_out, int out_size, void* d_ws, size_t ws_size,
                              hipStream_t stream) {
    const float* x  = (const float*)d_in[0];
    const float* W1 = (const float*)d_in[1];
    const float* b1 = (const float*)d_in[2];
    const float* W2 = (const float*)d_in[3];
    const float* b2 = (const float*)d_in[4];
    const float* W3 = (const float*)d_in[5];
    const float* b3 = (const float*)d_in[6];
    const float* W4 = (const float*)d_in[7];
    const float* b4 = (const float*)d_in[8];
    const float* W5 = (const float*)d_in[9];
    const float* b5 = (const float*)d_in[10];
    float* out = (float*)d_out;

    zero_C_kernel<<<3, P * P, 0, stream>>>();
    knn1_kernel<<<BB / SPB, NT, 0, stream>>>(x);
    l1_kernel<<<BB / SPB, NT, 0, stream>>>(x, W1, b1);
    l2_kernel<<<BB / SPB, NT, 0, stream>>>(W2, b2);
    tail_kernel<<<BB / SPB, NT, 0, stream>>>(W3, b3, W4, b4, W5, b5, out);
}

// Round 5
// 3202.549 us; speedup vs baseline: 1.7870x; 1.5533x over previous
//
#include <hip/hip_runtime.h>
#include <math.h>

#define BB 16384
#define P 20
#define NT 512
#define SPB 16

typedef short v8s __attribute__((ext_vector_type(8)));
typedef float f32x4 __attribute__((ext_vector_type(4)));

// ---- static device buffers: referenced ONLY inside device code (never passed
// as kernel args from host — that passes the host shadow and faults). ----
#define NELEM ((size_t)BB * P * 320)          // 209.7 MB each
__device__ unsigned int g_C[3][P * P];
__device__ __align__(16) unsigned short g_bufA[NELEM];  // z1 / z2 / z3 / h4
__device__ __align__(16) unsigned short g_bufB[NELEM];  // h1 / h2 / h3f
__device__ __align__(16) unsigned short g_W1b[320 * 128];
__device__ __align__(16) unsigned short g_W2b[128 * 320];
__device__ __align__(16) unsigned short g_W3b[64 * 128];
__device__ __align__(16) unsigned short g_W4b[112 * 1024];
__device__ __align__(16) float g_b1p[320];
__device__ __align__(16) float g_b2p[128];
__device__ __align__(16) float g_b3p[64];
__device__ __align__(16) float g_b4p[112];

__device__ inline float bf2f(unsigned short u) {
    union { unsigned int i; float f; } c; c.i = ((unsigned int)u) << 16; return c.f;
}
__device__ inline unsigned short f2bf(float f) {
    union { float f; unsigned int i; } c; c.f = f;
    unsigned int u = c.i + 0x7fffu + ((c.i >> 16) & 1u);  // RNE (no NaN in data)
    return (unsigned short)(u >> 16);
}

__global__ void zero_C_kernel() { g_C[blockIdx.x][threadIdx.x] = 0u; }

// Pad+convert weights/biases to bf16 (zero pads -> pad outputs relu(0+0)=0).
__global__ void prep_kernel(const float* __restrict__ W1, const float* __restrict__ b1,
                            const float* __restrict__ W2, const float* __restrict__ b2,
                            const float* __restrict__ W3, const float* __restrict__ b3,
                            const float* __restrict__ W4, const float* __restrict__ b4) {
    const int stride = gridDim.x * blockDim.x;
    const int id = blockIdx.x * blockDim.x + threadIdx.x;
    for (int i = id; i < 320 * 128; i += stride) { int n = i >> 7, k = i & 127;
        g_W1b[i] = (n < 300) ? f2bf(W1[n * 128 + k]) : 0; }
    for (int i = id; i < 128 * 320; i += stride) { int n = i / 320, k = i - n * 320;
        g_W2b[i] = (n < 100 && k < 300) ? f2bf(W2[n * 300 + k]) : 0; }
    for (int i = id; i < 64 * 128; i += stride) { int n = i >> 7, k = i & 127;
        g_W3b[i] = (n < 50 && k < 100) ? f2bf(W3[n * 100 + k]) : 0; }
    for (int i = id; i < 112 * 1024; i += stride) { int n = i >> 10, k = i & 1023;
        g_W4b[i] = (n < 100 && k < 1000) ? f2bf(W4[n * 1000 + k]) : 0; }
    for (int i = id; i < 320; i += stride) g_b1p[i] = (i < 300) ? b1[i] : 0.f;
    for (int i = id; i < 128; i += stride) g_b2p[i] = (i < 100) ? b2[i] : 0.f;
    for (int i = id; i < 64;  i += stride) g_b3p[i] = (i < 50)  ? b3[i] : 0.f;
    for (int i = id; i < 112; i += stride) g_b4p[i] = (i < 100) ? b4[i] : 0.f;
}

// ---------------- kNN machinery (verified rounds 2-3) ----------------

template<int DIN, int SH>
__device__ inline void stage_xf(const float* __restrict__ g, float* hs, int t) {
    const float4* src = (const float4*)g;
    for (int i = t; i < P * DIN / 4; i += NT) {
        float4 v = src[i];
        int r = (i * 4) / DIN, c = (i * 4) % DIN;
        *(float4*)(hs + r * SH + c) = v;
    }
}

template<int DIN, int SH>
__device__ inline void knn_accum(const float* hbuf, float* d2s,
                                 unsigned int* hist, int t) {
    const int p = t / P, q = t % P;
    float dotv = 0.f;
    if (t < P * P) {
        for (int d = 0; d < DIN; d += 4) {
            float4 a = *(const float4*)(hbuf + p * SH + d);
            float4 b = *(const float4*)(hbuf + q * SH + d);
            dotv += a.x * b.x + a.y * b.y + a.z * b.z + a.w * b.w;
        }
        d2s[t] = dotv;
    }
    __syncthreads();
    float dv = 0.f;
    if (t < P * P && p != q)
        dv = d2s[p * P + p] + d2s[q * P + q] - 2.f * dotv;
    __syncthreads();
    if (t < P * P) d2s[t] = dv;
    __syncthreads();
    if (t < P) {
        float pv = -3.0e38f; int pi = -1;
        for (int it = 0; it < 6; ++it) {
            float best = 3.0e38f; int bq = 0;
            for (int u = 0; u < P; ++u) {
                float vu = d2s[t * P + u];
                bool cand = (vu > pv) || (vu == pv && u > pi);
                if (cand && vu < best) { best = vu; bq = u; }
            }
            if (it > 0) atomicAdd(&hist[bq * P + t], 1u);
            pv = best; pi = bq;
        }
    }
}

__global__ __launch_bounds__(NT)
void knn1_kernel(const float* __restrict__ x) {
    __shared__ __align__(16) float xs[P * 132];
    __shared__ float d2s[P * P];
    __shared__ unsigned int hist[P * P];
    const int t = threadIdx.x;
    if (t < P * P) hist[t] = 0;
    for (int si = 0; si < SPB; ++si) {
        const size_t s = (size_t)blockIdx.x * SPB + si;
        __syncthreads();
        stage_xf<128, 132>(x + s * P * 128, xs, t);
        __syncthreads();
        knn_accum<128, 132>(xs, d2s, hist, t);
    }
    __syncthreads();
    if (t < P * P && hist[t]) atomicAdd(&g_C[0][t], hist[t]);
}

// kNN on bf16 h in g_bufB (pad cols exactly 0 -> harmless in dots)
template<int D, int CIDX>
__global__ __launch_bounds__(NT)
void knn_bf_kernel() {
    __shared__ __align__(16) float hs[P * D];
    __shared__ float d2s[P * P];
    __shared__ unsigned int hist[P * P];
    const int t = threadIdx.x;
    if (t < P * P) hist[t] = 0;
    for (int si = 0; si < SPB; ++si) {
        const size_t s = (size_t)blockIdx.x * SPB + si;
        __syncthreads();
        const unsigned short* src = g_bufB + s * (P * D);
        for (int i = t; i < P * D / 4; i += NT) {
            ushort4 u = *(const ushort4*)(src + i * 4);
            hs[i * 4 + 0] = bf2f(u.x); hs[i * 4 + 1] = bf2f(u.y);
            hs[i * 4 + 2] = bf2f(u.z); hs[i * 4 + 3] = bf2f(u.w);
        }
        __syncthreads();
        knn_accum<D, D>(hs, d2s, hist, t);
    }
    __syncthreads();
    if (t < P * P && hist[t]) atomicAdd(&g_C[CIDX][t], hist[t]);
}

__device__ inline void compute_M(const unsigned int* __restrict__ Cg,
                                 float* Ms, float* dinv, int t) {
    if (t < P * P) Ms[t] = (float)Cg[t];
    __syncthreads();
    if (t < P) {
        float deg = 1.f;
        for (int u = 0; u < P; ++u) deg += Ms[t * P + u];
        dinv[t] = 1.f / sqrtf(deg);
    }
    __syncthreads();
    if (t < P * P) {
        int v = t / P, u = t % P;
        float m = dinv[v] * Ms[t] * dinv[u];
        if (v == u) m += dinv[v] * dinv[v];
        Ms[t] = m;
    }
    __syncthreads();
}

// z[s,v,d] = sum_u M[v,u] h[s,u,d] -> bf16 into g_bufA. Each element touched
// exactly once (thread owns (s,d), loops u, writes all v) — memory-bound.
template<int D, bool INF32, int CIDX>
__global__ __launch_bounds__(NT)
void agg_kernel(const float* __restrict__ xin) {
    __shared__ float Ms[P * P];
    __shared__ float dinv[P];
    const int t = threadIdx.x;
    compute_M(g_C[CIDX], Ms, dinv, t);
    const unsigned int total = (unsigned int)BB * D;
    const unsigned int stride = gridDim.x * NT;
    for (unsigned int i = blockIdx.x * NT + t; i < total; i += stride) {
        const unsigned int s = i / D, d = i - s * D;
        const size_t base = (size_t)s * (P * D) + d;
        float acc[P];
#pragma unroll
        for (int v = 0; v < P; ++v) acc[v] = 0.f;
#pragma unroll
        for (int u = 0; u < P; ++u) {
            float xv = INF32 ? xin[base + u * D] : bf2f(g_bufB[base + u * D]);
#pragma unroll
            for (int v = 0; v < P; ++v) acc[v] += Ms[v * P + u] * xv;
        }
#pragma unroll
        for (int v = 0; v < P; ++v) g_bufA[base + (size_t)v * D] = f2bf(acc[v]);
    }
}

// ---------------- barrier-free streaming MFMA GEMM ----------------
// A-op = W rows (n as MFMA-m), B-op = z rows (m as MFMA-n). D-frag: lane&15 =
// output row m, (lane>>4)*4+reg = n (4 contiguous) -> packed stores.
// WSEL picks W/b globals; ATOB: A=bufA->bufB (true) or bufB->bufA (false).
template<int Kp, int Np, int ZR, bool FLAT, int WSEL, bool ATOB>
__global__ __launch_bounds__(256)
void gemm_kernel() {
    constexpr int NF = Np / 16, KS = Kp / 32;
    const unsigned short* __restrict__ Wb =
        (WSEL == 1) ? g_W1b : (WSEL == 2) ? g_W2b : (WSEL == 3) ? g_W3b : g_W4b;
    const float* __restrict__ bp =
        (WSEL == 1) ? g_b1p : (WSEL == 2) ? g_b2p : (WSEL == 3) ? g_b3p : g_b4p;
    const unsigned short* __restrict__ A = ATOB ? g_bufA : g_bufB;
    unsigned short* __restrict__ Hout = ATOB ? g_bufB : g_bufA;
    const int t = threadIdx.x, w = t >> 6, lane = t & 63;
    const int m15 = lane & 15, q = lane >> 4;
    const long row0 = (long)blockIdx.x * (4 * ZR * 16) + w * (ZR * 16);
    f32x4 acc[ZR][NF];
#pragma unroll
    for (int zr = 0; zr < ZR; ++zr)
#pragma unroll
        for (int nf = 0; nf < NF; ++nf) acc[zr][nf] = 0.f;
    const unsigned short* aBase = A + (row0 + m15) * Kp + q * 8;
    const unsigned short* wBase = Wb + m15 * Kp + q * 8;
    for (int ks = 0; ks < KS; ++ks) {
        v8s bz[ZR];
#pragma unroll
        for (int zr = 0; zr < ZR; ++zr)
            bz[zr] = *(const v8s*)(aBase + (size_t)zr * 16 * Kp + ks * 32);
#pragma unroll
        for (int nf = 0; nf < NF; ++nf) {
            v8s a = *(const v8s*)(wBase + (size_t)nf * 16 * Kp + ks * 32);
#pragma unroll
            for (int zr = 0; zr < ZR; ++zr)
                acc[zr][nf] = __builtin_amdgcn_mfma_f32_16x16x32_bf16(
                    a, bz[zr], acc[zr][nf], 0, 0, 0);
        }
    }
#pragma unroll
    for (int zr = 0; zr < ZR; ++zr) {
        const long m = row0 + zr * 16 + m15;
#pragma unroll
        for (int nf = 0; nf < NF; ++nf) {
            f32x4 b4 = *(const f32x4*)(bp + nf * 16 + q * 4);
            f32x4 c = acc[zr][nf];
            float v0 = fmaxf(c[0] + b4[0], 0.f), v1 = fmaxf(c[1] + b4[1], 0.f);
            float v2 = fmaxf(c[2] + b4[2], 0.f), v3 = fmaxf(c[3] + b4[3], 0.f);
            if (!FLAT) {
                ushort4 o; o.x = f2bf(v0); o.y = f2bf(v1); o.z = f2bf(v2); o.w = f2bf(v3);
                *(ushort4*)(Hout + (size_t)m * Np + nf * 16 + q * 4) = o;
            } else {
                // flat (B,1024): col = u*50 + n; n >= 50 dropped. Stale pad
                // cols 1000..1023 are harmless: W4b pad cols are zero.
                const int n0 = nf * 16 + q * 4;
                if (n0 <= 48) {
                    const long s = m / 20; const int u = (int)(m - s * 20);
                    unsigned short* base = Hout + (size_t)s * 1024 + u * 50 + n0;
                    unsigned int lo = (unsigned int)f2bf(v0) | ((unsigned int)f2bf(v1) << 16);
                    *(unsigned int*)(base) = lo;
                    if (n0 < 48) {
                        unsigned int hi = (unsigned int)f2bf(v2) | ((unsigned int)f2bf(v3) << 16);
                        *(unsigned int*)(base + 2) = hi;
                    }
                }
            }
        }
    }
}

// logits = W5 h4 + b5; softmax -> out. h4 in g_bufA (112-padded rows).
__global__ __launch_bounds__(256)
void head_kernel(const float* __restrict__ W5, const float* __restrict__ b5,
                 float* __restrict__ out) {
    __shared__ float w5s[300];
    __shared__ float b5s[3];
    const int t = threadIdx.x;
    for (int i = t; i < 300; i += 256) w5s[i] = W5[i];
    if (t < 3) b5s[t] = b5[t];
    __syncthreads();
    const int s = blockIdx.x * 256 + t;
    const unsigned short* h = g_bufA + (size_t)s * 112;
    float a0 = b5s[0], a1 = b5s[1], a2 = b5s[2];
    for (int k = 0; k < 100; ++k) {
        float hv = bf2f(h[k]);
        a0 += hv * w5s[k]; a1 += hv * w5s[100 + k]; a2 += hv * w5s[200 + k];
    }
    float m = fmaxf(a0, fmaxf(a1, a2));
    float e0 = expf(a0 - m), e1 = expf(a1 - m), e2 = expf(a2 - m);
    float inv = 1.f / (e0 + e1 + e2);
    out[(size_t)s * 3 + 0] = e0 * inv;
    out[(size_t)s * 3 + 1] = e1 * inv;
    out[(size_t)s * 3 + 2] = e2 * inv;
}

extern "C" void kernel_launch(void* const* d_in, const int* in_sizes, int n_in,
                              void* d_out, int out_size, void* d_ws, size_t ws_size,
                              hipStream_t stream) {
    const float* x  = (const float*)d_in[0];
    const float* W1 = (const float*)d_in[1];
    const float* b1 = (const float*)d_in[2];
    const float* W2 = (const float*)d_in[3];
    const float* b2 = (const float*)d_in[4];
    const float* W3 = (const float*)d_in[5];
    const float* b3 = (const float*)d_in[6];
    const float* W4 = (const float*)d_in[7];
    const float* b4 = (const float*)d_in[8];
    const float* W5 = (const float*)d_in[9];
    const float* b5 = (const float*)d_in[10];
    float* out = (float*)d_out;

    zero_C_kernel<<<3, P * P, 0, stream>>>();
    prep_kernel<<<256, 256, 0, stream>>>(W1, b1, W2, b2, W3, b3, W4, b4);

    knn1_kernel<<<BB / SPB, NT, 0, stream>>>(x);
    agg_kernel<128, true, 0><<<1024, NT, 0, stream>>>(x);            // x -> z1(A)
    gemm_kernel<128, 320, 2, false, 1, true><<<2560, 256, 0, stream>>>();   // z1 -> h1(B)

    knn_bf_kernel<320, 1><<<BB / SPB, NT, 0, stream>>>();            // h1 -> C1
    agg_kernel<320, false, 1><<<1024, NT, 0, stream>>>(nullptr);     // h1 -> z2(A)
    gemm_kernel<320, 128, 4, false, 2, true><<<1280, 256, 0, stream>>>();   // z2 -> h2(B)

    knn_bf_kernel<128, 2><<<BB / SPB, NT, 0, stream>>>();            // h2 -> C2
    agg_kernel<128, false, 2><<<1024, NT, 0, stream>>>(nullptr);     // h2 -> z3(A)
    gemm_kernel<128, 64, 4, true, 3, true><<<1280, 256, 0, stream>>>();     // z3 -> h3f(B)

    gemm_kernel<1024, 112, 1, false, 4, false><<<256, 256, 0, stream>>>();  // h3f -> h4(A)
    head_kernel<<<BB / 256, 256, 0, stream>>>(W5, b5, out);
}

// Round 6
// 2035.650 us; speedup vs baseline: 2.8113x; 1.5732x over previous
//
#include <hip/hip_runtime.h>
#include <math.h>

#define BB 16384
#define P 20
#define NT 512
#define SPB 16

typedef short v8s __attribute__((ext_vector_type(8)));
typedef float f32x4 __attribute__((ext_vector_type(4)));
typedef float f32x16 __attribute__((ext_vector_type(16)));

// ---- static device buffers: referenced ONLY inside device code (never passed
// as kernel args from host — that passes the host shadow and faults). ----
// +4096 pad: knn_mfma reads rows m=20..31 of the last samples (garbage, unused).
#define NELEM ((size_t)BB * P * 320)          // 209.7 MB each
__device__ unsigned int g_C[3][P * P];
__device__ __align__(16) unsigned short g_bufA[NELEM + 4096];  // z1 / z2 / z3 / h4
__device__ __align__(16) unsigned short g_bufB[NELEM + 4096];  // h1 / h2 / h3f
__device__ __align__(16) unsigned short g_W1b[320 * 128];
__device__ __align__(16) unsigned short g_W2b[128 * 320];
__device__ __align__(16) unsigned short g_W3b[64 * 128];
__device__ __align__(16) unsigned short g_W4b[112 * 1024];
__device__ __align__(16) float g_b1p[320];
__device__ __align__(16) float g_b2p[128];
__device__ __align__(16) float g_b3p[64];
__device__ __align__(16) float g_b4p[112];

__device__ inline float bf2f(unsigned short u) {
    union { unsigned int i; float f; } c; c.i = ((unsigned int)u) << 16; return c.f;
}
__device__ inline unsigned short f2bf(float f) {
    union { float f; unsigned int i; } c; c.f = f;
    unsigned int u = c.i + 0x7fffu + ((c.i >> 16) & 1u);  // RNE (no NaN in data)
    return (unsigned short)(u >> 16);
}

__global__ void zero_C_kernel() { g_C[blockIdx.x][threadIdx.x] = 0u; }

// Pad+convert weights/biases to bf16 (zero pads -> pad outputs relu(0+0)=0).
__global__ void prep_kernel(const float* __restrict__ W1, const float* __restrict__ b1,
                            const float* __restrict__ W2, const float* __restrict__ b2,
                            const float* __restrict__ W3, const float* __restrict__ b3,
                            const float* __restrict__ W4, const float* __restrict__ b4) {
    const int stride = gridDim.x * blockDim.x;
    const int id = blockIdx.x * blockDim.x + threadIdx.x;
    for (int i = id; i < 320 * 128; i += stride) { int n = i >> 7, k = i & 127;
        g_W1b[i] = (n < 300) ? f2bf(W1[n * 128 + k]) : 0; }
    for (int i = id; i < 128 * 320; i += stride) { int n = i / 320, k = i - n * 320;
        g_W2b[i] = (n < 100 && k < 300) ? f2bf(W2[n * 300 + k]) : 0; }
    for (int i = id; i < 64 * 128; i += stride) { int n = i >> 7, k = i & 127;
        g_W3b[i] = (n < 50 && k < 100) ? f2bf(W3[n * 100 + k]) : 0; }
    for (int i = id; i < 112 * 1024; i += stride) { int n = i >> 10, k = i & 1023;
        g_W4b[i] = (n < 100 && k < 1000) ? f2bf(W4[n * 1000 + k]) : 0; }
    for (int i = id; i < 320; i += stride) g_b1p[i] = (i < 300) ? b1[i] : 0.f;
    for (int i = id; i < 128; i += stride) g_b2p[i] = (i < 100) ? b2[i] : 0.f;
    for (int i = id; i < 64;  i += stride) g_b3p[i] = (i < 50)  ? b3[i] : 0.f;
    for (int i = id; i < 112; i += stride) g_b4p[i] = (i < 100) ? b4[i] : 0.f;
}

// ---------------- kNN: fp32 path for layer 1 (verified rounds 2-5) ----------

template<int DIN, int SH>
__device__ inline void stage_xf(const float* __restrict__ g, float* hs, int t) {
    const float4* src = (const float4*)g;
    for (int i = t; i < P * DIN / 4; i += NT) {
        float4 v = src[i];
        int r = (i * 4) / DIN, c = (i * 4) % DIN;
        *(float4*)(hs + r * SH + c) = v;
    }
}

template<int DIN, int SH>
__device__ inline void knn_accum(const float* hbuf, float* d2s,
                                 unsigned int* hist, int t) {
    const int p = t / P, q = t % P;
    float dotv = 0.f;
    if (t < P * P) {
        for (int d = 0; d < DIN; d += 4) {
            float4 a = *(const float4*)(hbuf + p * SH + d);
            float4 b = *(const float4*)(hbuf + q * SH + d);
            dotv += a.x * b.x + a.y * b.y + a.z * b.z + a.w * b.w;
        }
        d2s[t] = dotv;
    }
    __syncthreads();
    float dv = 0.f;
    if (t < P * P && p != q)
        dv = d2s[p * P + p] + d2s[q * P + q] - 2.f * dotv;
    __syncthreads();
    if (t < P * P) d2s[t] = dv;
    __syncthreads();
    if (t < P) {
        float pv = -3.0e38f; int pi = -1;
        for (int it = 0; it < 6; ++it) {
            float best = 3.0e38f; int bq = 0;
            for (int u = 0; u < P; ++u) {
                float vu = d2s[t * P + u];
                bool cand = (vu > pv) || (vu == pv && u > pi);
                if (cand && vu < best) { best = vu; bq = u; }
            }
            if (it > 0) atomicAdd(&hist[bq * P + t], 1u);
            pv = best; pi = bq;
        }
    }
}

__global__ __launch_bounds__(NT)
void knn1_kernel(const float* __restrict__ x) {
    __shared__ __align__(16) float xs[P * 132];
    __shared__ float d2s[P * P];
    __shared__ unsigned int hist[P * P];
    const int t = threadIdx.x;
    if (t < P * P) hist[t] = 0;
    for (int si = 0; si < SPB; ++si) {
        const size_t s = (size_t)blockIdx.x * SPB + si;
        __syncthreads();
        stage_xf<128, 132>(x + s * P * 128, xs, t);
        __syncthreads();
        knn_accum<128, 132>(xs, d2s, hist, t);
    }
    __syncthreads();
    if (t < P * P && hist[t]) atomicAdd(&g_C[0][t], hist[t]);
}

// ---------------- kNN via MFMA Gram: G = Z Z^T per sample -------------------
// One wave per sample. Same v8s fragment passed as A and B: A[m][k] and
// B[k][n] layouts coincide for row-major Z (m/n = lane&31, k = (lane>>5)*8+j).
// C/D: col=lane&31, row=(reg&3)+8*(reg>>2)+4*(lane>>5)  [m74/m101 verified].
// Rows 20..31 are garbage (OOB-pad reads) but their G entries are never used.
template<int D, int CIDX>
__global__ __launch_bounds__(NT)
void knn_mfma_kernel() {
    __shared__ float Gs[8][P * 21];
    __shared__ unsigned int hist[P * P];
    const int t = threadIdx.x, w = t >> 6, lane = t & 63;
    const int m31 = lane & 31, half = lane >> 5;
    for (int i = t; i < P * P; i += NT) hist[i] = 0;
    for (int pass = 0; pass < 2; ++pass) {
        const size_t s = (size_t)blockIdx.x * 16 + pass * 8 + w;
        const unsigned short* rp = g_bufB + s * (P * D) + (size_t)m31 * D + half * 8;
        f32x16 acc;
#pragma unroll
        for (int i = 0; i < 16; ++i) acc[i] = 0.f;
        for (int ks = 0; ks < D / 16; ++ks) {
            v8s z = *(const v8s*)(rp + ks * 16);
            acc = __builtin_amdgcn_mfma_f32_32x32x16_bf16(z, z, acc, 0, 0, 0);
        }
        float* G = &Gs[w][0];
        if (m31 < P) {
#pragma unroll
            for (int r = 0; r < 16; ++r) {
                int row = (r & 3) + 8 * (r >> 2) + 4 * half;
                if (row < P) G[row * 21 + m31] = acc[r];
            }
        }
        __syncthreads();   // LDS write->read ordering (uniform across waves)
        if (lane < P) {
            const int p = lane;
            float d2[P];
            const float gpp = G[p * 21 + p];
#pragma unroll
            for (int u = 0; u < P; ++u)
                d2[u] = (u == p) ? 0.f : gpp + G[u * 21 + u] - 2.f * G[p * 21 + u];
            float pv = -3.0e38f; int pi = -1;
            for (int it = 0; it < 6; ++it) {
                float best = 3.0e38f; int bq = 0;
#pragma unroll
                for (int u = 0; u < P; ++u) {
                    float vu = d2[u];
                    bool cand = (vu > pv) || (vu == pv && u > pi);
                    if (cand && vu < best) { best = vu; bq = u; }
                }
                if (it > 0) atomicAdd(&hist[bq * P + p], 1u);
                pv = best; pi = bq;
            }
        }
        __syncthreads();   // Gs reused next pass; hist visibility at flush
    }
    if (t < P * P && hist[t]) atomicAdd(&g_C[CIDX][t], hist[t]);
}

__device__ inline void compute_M(const unsigned int* __restrict__ Cg,
                                 float* Ms, float* dinv, int t) {
    if (t < P * P) Ms[t] = (float)Cg[t];
    __syncthreads();
    if (t < P) {
        float deg = 1.f;
        for (int u = 0; u < P; ++u) deg += Ms[t * P + u];
        dinv[t] = 1.f / sqrtf(deg);
    }
    __syncthreads();
    if (t < P * P) {
        int v = t / P, u = t % P;
        float m = dinv[v] * Ms[t] * dinv[u];
        if (v == u) m += dinv[v] * dinv[v];
        Ms[t] = m;
    }
    __syncthreads();
}

// z[s,v,d] = sum_u M[v,u] h[s,u,d] -> bf16 into g_bufA. Memory-bound.
template<int D, bool INF32, int CIDX>
__global__ __launch_bounds__(NT)
void agg_kernel(const float* __restrict__ xin) {
    __shared__ float Ms[P * P];
    __shared__ float dinv[P];
    const int t = threadIdx.x;
    compute_M(g_C[CIDX], Ms, dinv, t);
    const unsigned int total = (unsigned int)BB * D;
    const unsigned int stride = gridDim.x * NT;
    for (unsigned int i = blockIdx.x * NT + t; i < total; i += stride) {
        const unsigned int s = i / D, d = i - s * D;
        const size_t base = (size_t)s * (P * D) + d;
        float acc[P];
#pragma unroll
        for (int v = 0; v < P; ++v) acc[v] = 0.f;
#pragma unroll
        for (int u = 0; u < P; ++u) {
            float xv = INF32 ? xin[base + u * D] : bf2f(g_bufB[base + u * D]);
#pragma unroll
            for (int v = 0; v < P; ++v) acc[v] += Ms[v * P + u] * xv;
        }
#pragma unroll
        for (int v = 0; v < P; ++v) g_bufA[base + (size_t)v * D] = f2bf(acc[v]);
    }
}

// ---------------- barrier-free streaming MFMA GEMM (verified r5) ------------
template<int Kp, int Np, int ZR, bool FLAT, int WSEL, bool ATOB>
__global__ __launch_bounds__(256)
void gemm_kernel() {
    constexpr int NF = Np / 16, KS = Kp / 32;
    const unsigned short* __restrict__ Wb =
        (WSEL == 1) ? g_W1b : (WSEL == 2) ? g_W2b : (WSEL == 3) ? g_W3b : g_W4b;
    const float* __restrict__ bp =
        (WSEL == 1) ? g_b1p : (WSEL == 2) ? g_b2p : (WSEL == 3) ? g_b3p : g_b4p;
    const unsigned short* __restrict__ A = ATOB ? g_bufA : g_bufB;
    unsigned short* __restrict__ Hout = ATOB ? g_bufB : g_bufA;
    const int t = threadIdx.x, w = t >> 6, lane = t & 63;
    const int m15 = lane & 15, q = lane >> 4;
    const long row0 = (long)blockIdx.x * (4 * ZR * 16) + w * (ZR * 16);
    f32x4 acc[ZR][NF];
#pragma unroll
    for (int zr = 0; zr < ZR; ++zr)
#pragma unroll
        for (int nf = 0; nf < NF; ++nf) acc[zr][nf] = 0.f;
    const unsigned short* aBase = A + (row0 + m15) * Kp + q * 8;
    const unsigned short* wBase = Wb + m15 * Kp + q * 8;
    for (int ks = 0; ks < KS; ++ks) {
        v8s bz[ZR];
#pragma unroll
        for (int zr = 0; zr < ZR; ++zr)
            bz[zr] = *(const v8s*)(aBase + (size_t)zr * 16 * Kp + ks * 32);
#pragma unroll
        for (int nf = 0; nf < NF; ++nf) {
            v8s a = *(const v8s*)(wBase + (size_t)nf * 16 * Kp + ks * 32);
#pragma unroll
            for (int zr = 0; zr < ZR; ++zr)
                acc[zr][nf] = __builtin_amdgcn_mfma_f32_16x16x32_bf16(
                    a, bz[zr], acc[zr][nf], 0, 0, 0);
        }
    }
#pragma unroll
    for (int zr = 0; zr < ZR; ++zr) {
        const long m = row0 + zr * 16 + m15;
#pragma unroll
        for (int nf = 0; nf < NF; ++nf) {
            f32x4 b4 = *(const f32x4*)(bp + nf * 16 + q * 4);
            f32x4 c = acc[zr][nf];
            float v0 = fmaxf(c[0] + b4[0], 0.f), v1 = fmaxf(c[1] + b4[1], 0.f);
            float v2 = fmaxf(c[2] + b4[2], 0.f), v3 = fmaxf(c[3] + b4[3], 0.f);
            if (!FLAT) {
                ushort4 o; o.x = f2bf(v0); o.y = f2bf(v1); o.z = f2bf(v2); o.w = f2bf(v3);
                *(ushort4*)(Hout + (size_t)m * Np + nf * 16 + q * 4) = o;
            } else {
                // flat (B,1024): col = u*50 + n; n >= 50 dropped. Stale pad
                // cols 1000..1023 are harmless: W4b pad cols are zero.
                const int n0 = nf * 16 + q * 4;
                if (n0 <= 48) {
                    const long s = m / 20; const int u = (int)(m - s * 20);
                    unsigned short* base = Hout + (size_t)s * 1024 + u * 50 + n0;
                    unsigned int lo = (unsigned int)f2bf(v0) | ((unsigned int)f2bf(v1) << 16);
                    *(unsigned int*)(base) = lo;
                    if (n0 < 48) {
                        unsigned int hi = (unsigned int)f2bf(v2) | ((unsigned int)f2bf(v3) << 16);
                        *(unsigned int*)(base + 2) = hi;
                    }
                }
            }
        }
    }
}

// logits = W5 h4 + b5; softmax -> out. h4 in g_bufA (112-padded rows).
__global__ __launch_bounds__(256)
void head_kernel(const float* __restrict__ W5, const float* __restrict__ b5,
                 float* __restrict__ out) {
    __shared__ float w5s[300];
    __shared__ float b5s[3];
    const int t = threadIdx.x;
    for (int i = t; i < 300; i += 256) w5s[i] = W5[i];
    if (t < 3) b5s[t] = b5[t];
    __syncthreads();
    const int s = blockIdx.x * 256 + t;
    const unsigned short* h = g_bufA + (size_t)s * 112;
    float a0 = b5s[0], a1 = b5s[1], a2 = b5s[2];
    for (int k = 0; k < 100; ++k) {
        float hv = bf2f(h[k]);
        a0 += hv * w5s[k]; a1 += hv * w5s[100 + k]; a2 += hv * w5s[200 + k];
    }
    float m = fmaxf(a0, fmaxf(a1, a2));
    float e0 = expf(a0 - m), e1 = expf(a1 - m), e2 = expf(a2 - m);
    float inv = 1.f / (e0 + e1 + e2);
    out[(size_t)s * 3 + 0] = e0 * inv;
    out[(size_t)s * 3 + 1] = e1 * inv;
    out[(size_t)s * 3 + 2] = e2 * inv;
}

extern "C" void kernel_launch(void* const* d_in, const int* in_sizes, int n_in,
                              void* d_out, int out_size, void* d_ws, size_t ws_size,
                              hipStream_t stream) {
    const float* x  = (const float*)d_in[0];
    const float* W1 = (const float*)d_in[1];
    const float* b1 = (const float*)d_in[2];
    const float* W2 = (const float*)d_in[3];
    const float* b2 = (const float*)d_in[4];
    const float* W3 = (const float*)d_in[5];
    const float* b3 = (const float*)d_in[6];
    const float* W4 = (const float*)d_in[7];
    const float* b4 = (const float*)d_in[8];
    const float* W5 = (const float*)d_in[9];
    const float* b5 = (const float*)d_in[10];
    float* out = (float*)d_out;

    zero_C_kernel<<<3, P * P, 0, stream>>>();
    prep_kernel<<<256, 256, 0, stream>>>(W1, b1, W2, b2, W3, b3, W4, b4);

    knn1_kernel<<<BB / SPB, NT, 0, stream>>>(x);
    agg_kernel<128, true, 0><<<1024, NT, 0, stream>>>(x);            // x -> z1(A)
    gemm_kernel<128, 320, 2, false, 1, true><<<2560, 256, 0, stream>>>();   // z1 -> h1(B)

    knn_mfma_kernel<320, 1><<<BB / 16, NT, 0, stream>>>();           // h1 -> C1
    agg_kernel<320, false, 1><<<1024, NT, 0, stream>>>(nullptr);     // h1 -> z2(A)
    gemm_kernel<320, 128, 4, false, 2, true><<<1280, 256, 0, stream>>>();   // z2 -> h2(B)

    knn_mfma_kernel<128, 2><<<BB / 16, NT, 0, stream>>>();           // h2 -> C2
    agg_kernel<128, false, 2><<<1024, NT, 0, stream>>>(nullptr);     // h2 -> z3(A)
    gemm_kernel<128, 64, 4, true, 3, true><<<1280, 256, 0, stream>>>();     // z3 -> h3f(B)

    gemm_kernel<1024, 112, 1, false, 4, false><<<256, 256, 0, stream>>>();  // h3f -> h4(A)
    head_kernel<<<BB / 256, 256, 0, stream>>>(W5, b5, out);
}

// Round 7
// 1299.405 us; speedup vs baseline: 4.4042x; 1.5666x over previous
//
#include <hip/hip_runtime.h>
#include <math.h>

#define BB 16384
#define P 20
#define NT 512
#define SPB 16

typedef short v8s __attribute__((ext_vector_type(8)));
typedef float f32x4 __attribute__((ext_vector_type(4)));
typedef float f32x16 __attribute__((ext_vector_type(16)));

// ---- static device buffers: referenced ONLY inside device code (never passed
// as kernel args from host — that passes the host shadow and faults). ----
// +4096 pad: knn_mfma reads rows m=20..31 of the last samples (garbage, unused).
#define NELEM ((size_t)BB * P * 320)          // 209.7 MB each
__device__ unsigned int g_C[3][P * P];
__device__ __align__(16) unsigned short g_bufA[NELEM + 4096];  // z1 / z2 / z3 / h4
__device__ __align__(16) unsigned short g_bufB[NELEM + 4096];  // h1 / h2 / h3f
__device__ __align__(16) unsigned short g_W1b[320 * 128];
__device__ __align__(16) unsigned short g_W2b[128 * 320];
__device__ __align__(16) unsigned short g_W3b[64 * 128];
__device__ __align__(16) unsigned short g_W4b[112 * 1024];
__device__ __align__(16) float g_b1p[320];
__device__ __align__(16) float g_b2p[128];
__device__ __align__(16) float g_b3p[64];
__device__ __align__(16) float g_b4p[112];

__device__ inline float bf2f(unsigned short u) {
    union { unsigned int i; float f; } c; c.i = ((unsigned int)u) << 16; return c.f;
}
__device__ inline unsigned short f2bf(float f) {
    union { float f; unsigned int i; } c; c.f = f;
    unsigned int u = c.i + 0x7fffu + ((c.i >> 16) & 1u);  // RNE (no NaN in data)
    return (unsigned short)(u >> 16);
}

__global__ void zero_C_kernel() { g_C[blockIdx.x][threadIdx.x] = 0u; }

// Pad+convert weights/biases to bf16 (zero pads -> pad outputs relu(0+0)=0).
__global__ void prep_kernel(const float* __restrict__ W1, const float* __restrict__ b1,
                            const float* __restrict__ W2, const float* __restrict__ b2,
                            const float* __restrict__ W3, const float* __restrict__ b3,
                            const float* __restrict__ W4, const float* __restrict__ b4) {
    const int stride = gridDim.x * blockDim.x;
    const int id = blockIdx.x * blockDim.x + threadIdx.x;
    for (int i = id; i < 320 * 128; i += stride) { int n = i >> 7, k = i & 127;
        g_W1b[i] = (n < 300) ? f2bf(W1[n * 128 + k]) : 0; }
    for (int i = id; i < 128 * 320; i += stride) { int n = i / 320, k = i - n * 320;
        g_W2b[i] = (n < 100 && k < 300) ? f2bf(W2[n * 300 + k]) : 0; }
    for (int i = id; i < 64 * 128; i += stride) { int n = i >> 7, k = i & 127;
        g_W3b[i] = (n < 50 && k < 100) ? f2bf(W3[n * 100 + k]) : 0; }
    for (int i = id; i < 112 * 1024; i += stride) { int n = i >> 10, k = i & 1023;
        g_W4b[i] = (n < 100 && k < 1000) ? f2bf(W4[n * 1000 + k]) : 0; }
    for (int i = id; i < 320; i += stride) g_b1p[i] = (i < 300) ? b1[i] : 0.f;
    for (int i = id; i < 128; i += stride) g_b2p[i] = (i < 100) ? b2[i] : 0.f;
    for (int i = id; i < 64;  i += stride) g_b3p[i] = (i < 50)  ? b3[i] : 0.f;
    for (int i = id; i < 112; i += stride) g_b4p[i] = (i < 100) ? b4[i] : 0.f;
}

// ---------------- kNN: fp32 path for layer 1 (verified rounds 2-6) ----------

template<int DIN, int SH>
__device__ inline void stage_xf(const float* __restrict__ g, float* hs, int t) {
    const float4* src = (const float4*)g;
    for (int i = t; i < P * DIN / 4; i += NT) {
        float4 v = src[i];
        int r = (i * 4) / DIN, c = (i * 4) % DIN;
        *(float4*)(hs + r * SH + c) = v;
    }
}

template<int DIN, int SH>
__device__ inline void knn_accum(const float* hbuf, float* d2s,
                                 unsigned int* hist, int t) {
    const int p = t / P, q = t % P;
    float dotv = 0.f;
    if (t < P * P) {
        for (int d = 0; d < DIN; d += 4) {
            float4 a = *(const float4*)(hbuf + p * SH + d);
            float4 b = *(const float4*)(hbuf + q * SH + d);
            dotv += a.x * b.x + a.y * b.y + a.z * b.z + a.w * b.w;
        }
        d2s[t] = dotv;
    }
    __syncthreads();
    float dv = 0.f;
    if (t < P * P && p != q)
        dv = d2s[p * P + p] + d2s[q * P + q] - 2.f * dotv;
    __syncthreads();
    if (t < P * P) d2s[t] = dv;
    __syncthreads();
    if (t < P) {
        float pv = -3.0e38f; int pi = -1;
        for (int it = 0; it < 6; ++it) {
            float best = 3.0e38f; int bq = 0;
            for (int u = 0; u < P; ++u) {
                float vu = d2s[t * P + u];
                bool cand = (vu > pv) || (vu == pv && u > pi);
                if (cand && vu < best) { best = vu; bq = u; }
            }
            if (it > 0) atomicAdd(&hist[bq * P + t], 1u);
            pv = best; pi = bq;
        }
    }
}

__global__ __launch_bounds__(NT)
void knn1_kernel(const float* __restrict__ x) {
    __shared__ __align__(16) float xs[P * 132];
    __shared__ float d2s[P * P];
    __shared__ unsigned int hist[P * P];
    const int t = threadIdx.x;
    if (t < P * P) hist[t] = 0;
    for (int si = 0; si < SPB; ++si) {
        const size_t s = (size_t)blockIdx.x * SPB + si;
        __syncthreads();
        stage_xf<128, 132>(x + s * P * 128, xs, t);
        __syncthreads();
        knn_accum<128, 132>(xs, d2s, hist, t);
    }
    __syncthreads();
    if (t < P * P && hist[t]) atomicAdd(&g_C[0][t], hist[t]);
}

// ---------------- kNN via MFMA Gram: G = Z Z^T per sample (verified r6) -----
template<int D, int CIDX>
__global__ __launch_bounds__(NT)
void knn_mfma_kernel() {
    __shared__ float Gs[8][P * 21];
    __shared__ unsigned int hist[P * P];
    const int t = threadIdx.x, w = t >> 6, lane = t & 63;
    const int m31 = lane & 31, half = lane >> 5;
    for (int i = t; i < P * P; i += NT) hist[i] = 0;
    for (int pass = 0; pass < 2; ++pass) {
        const size_t s = (size_t)blockIdx.x * 16 + pass * 8 + w;
        const unsigned short* rp = g_bufB + s * (P * D) + (size_t)m31 * D + half * 8;
        f32x16 acc;
#pragma unroll
        for (int i = 0; i < 16; ++i) acc[i] = 0.f;
        for (int ks = 0; ks < D / 16; ++ks) {
            v8s z = *(const v8s*)(rp + ks * 16);
            acc = __builtin_amdgcn_mfma_f32_32x32x16_bf16(z, z, acc, 0, 0, 0);
        }
        float* G = &Gs[w][0];
        if (m31 < P) {
#pragma unroll
            for (int r = 0; r < 16; ++r) {
                int row = (r & 3) + 8 * (r >> 2) + 4 * half;
                if (row < P) G[row * 21 + m31] = acc[r];
            }
        }
        __syncthreads();
        if (lane < P) {
            const int p = lane;
            float d2[P];
            const float gpp = G[p * 21 + p];
#pragma unroll
            for (int u = 0; u < P; ++u)
                d2[u] = (u == p) ? 0.f : gpp + G[u * 21 + u] - 2.f * G[p * 21 + u];
            float pv = -3.0e38f; int pi = -1;
            for (int it = 0; it < 6; ++it) {
                float best = 3.0e38f; int bq = 0;
#pragma unroll
                for (int u = 0; u < P; ++u) {
                    float vu = d2[u];
                    bool cand = (vu > pv) || (vu == pv && u > pi);
                    if (cand && vu < best) { best = vu; bq = u; }
                }
                if (it > 0) atomicAdd(&hist[bq * P + p], 1u);
                pv = best; pi = bq;
            }
        }
        __syncthreads();
    }
    if (t < P * P && hist[t]) atomicAdd(&g_C[CIDX][t], hist[t]);
}

// compute_M for 256-thread blocks (strided loops)
__device__ inline void compute_M_256(const unsigned int* __restrict__ Cg,
                                     float* Ms, float* dinv, int t) {
    for (int i = t; i < P * P; i += 256) Ms[i] = (float)Cg[i];
    __syncthreads();
    if (t < P) {
        float deg = 1.f;
        for (int u = 0; u < P; ++u) deg += Ms[t * P + u];
        dinv[t] = 1.f / sqrtf(deg);
    }
    __syncthreads();
    for (int i = t; i < P * P; i += 256) {
        int v = i / P, u = i - v * P;
        float m = dinv[v] * Ms[i] * dinv[u];
        if (v == u) m += dinv[v] * dinv[v];
        Ms[i] = m;
    }
    __syncthreads();
}

// ---------------- agg: LDS-staged, vectorized (round-7 rewrite) -------------
// z[s,v,:] = sum_u M[v,u] h[s,u,:]. Block stages SAMP whole samples (fp32 in
// LDS, 16B coalesced global loads, each element fetched once), then computes
// 4-v register blocks per float4 chunk (h chunk read once per 4 v's), packed
// 8B bf16 stores. All LDS accesses lane-contiguous -> conflict-free.
template<int D, bool INF32, int CIDX, int SAMP>
__global__ __launch_bounds__(256)
void agg_kernel(const float* __restrict__ xin) {
    __shared__ float Ms[P * P];
    __shared__ float dinv[P];
    __shared__ __align__(16) float hsf[SAMP][P][D];
    const int t = threadIdx.x;
    compute_M_256(g_C[CIDX], Ms, dinv, t);
    constexpr int C4 = D / 4;               // float4 chunks per row
    for (long s0 = (long)blockIdx.x * SAMP; s0 < BB; s0 += (long)gridDim.x * SAMP) {
        __syncthreads();                    // hsf reuse guard
        if (INF32) {
            const float4* src = (const float4*)(xin + s0 * (P * D));
            for (int i = t; i < SAMP * P * C4; i += 256) {
                float4 v = src[i];
                int r = i / C4, c = i - r * C4;
                *(float4*)&hsf[r / P][r % P][c * 4] = v;
            }
        } else {
            const ushort4* src = (const ushort4*)(g_bufB + s0 * (P * D));
            for (int i = t; i < SAMP * P * C4; i += 256) {
                ushort4 u = src[i];
                int r = i / C4, c = i - r * C4;
                float4 f; f.x = bf2f(u.x); f.y = bf2f(u.y);
                f.z = bf2f(u.z); f.w = bf2f(u.w);
                *(float4*)&hsf[r / P][r % P][c * 4] = f;
            }
        }
        __syncthreads();
        // items: (smp, vg of 4 v's, c4). 5 v-groups per sample.
        for (int i = t; i < SAMP * 5 * C4; i += 256) {
            const int c4 = i % C4;
            const int g = i / C4;
            const int smp = g / 5, v0 = (g - smp * 5) * 4;
            float4 a0 = {0,0,0,0}, a1 = {0,0,0,0}, a2 = {0,0,0,0}, a3 = {0,0,0,0};
#pragma unroll
            for (int u = 0; u < P; ++u) {
                float4 h = *(const float4*)&hsf[smp][u][c4 * 4];
                float m0 = Ms[(v0 + 0) * P + u], m1 = Ms[(v0 + 1) * P + u];
                float m2 = Ms[(v0 + 2) * P + u], m3 = Ms[(v0 + 3) * P + u];
                a0.x += m0*h.x; a0.y += m0*h.y; a0.z += m0*h.z; a0.w += m0*h.w;
                a1.x += m1*h.x; a1.y += m1*h.y; a1.z += m1*h.z; a1.w += m1*h.w;
                a2.x += m2*h.x; a2.y += m2*h.y; a2.z += m2*h.z; a2.w += m2*h.w;
                a3.x += m3*h.x; a3.y += m3*h.y; a3.z += m3*h.z; a3.w += m3*h.w;
            }
            unsigned short* zb = g_bufA + (s0 + smp) * (size_t)(P * D) + c4 * 4;
            ushort4 o;
            o.x = f2bf(a0.x); o.y = f2bf(a0.y); o.z = f2bf(a0.z); o.w = f2bf(a0.w);
            *(ushort4*)(zb + (size_t)(v0 + 0) * D) = o;
            o.x = f2bf(a1.x); o.y = f2bf(a1.y); o.z = f2bf(a1.z); o.w = f2bf(a1.w);
            *(ushort4*)(zb + (size_t)(v0 + 1) * D) = o;
            o.x = f2bf(a2.x); o.y = f2bf(a2.y); o.z = f2bf(a2.z); o.w = f2bf(a2.w);
            *(ushort4*)(zb + (size_t)(v0 + 2) * D) = o;
            o.x = f2bf(a3.x); o.y = f2bf(a3.y); o.z = f2bf(a3.z); o.w = f2bf(a3.w);
            *(ushort4*)(zb + (size_t)(v0 + 3) * D) = o;
        }
    }
}

// ---------------- barrier-free streaming MFMA GEMM (verified r5/r6) ---------
template<int Kp, int Np, int ZR, bool FLAT, int WSEL, bool ATOB>
__global__ __launch_bounds__(256)
void gemm_kernel() {
    constexpr int NF = Np / 16, KS = Kp / 32;
    const unsigned short* __restrict__ Wb =
        (WSEL == 1) ? g_W1b : (WSEL == 2) ? g_W2b : (WSEL == 3) ? g_W3b : g_W4b;
    const float* __restrict__ bp =
        (WSEL == 1) ? g_b1p : (WSEL == 2) ? g_b2p : (WSEL == 3) ? g_b3p : g_b4p;
    const unsigned short* __restrict__ A = ATOB ? g_bufA : g_bufB;
    unsigned short* __restrict__ Hout = ATOB ? g_bufB : g_bufA;
    const int t = threadIdx.x, w = t >> 6, lane = t & 63;
    const int m15 = lane & 15, q = lane >> 4;
    const long row0 = (long)blockIdx.x * (4 * ZR * 16) + w * (ZR * 16);
    f32x4 acc[ZR][NF];
#pragma unroll
    for (int zr = 0; zr < ZR; ++zr)
#pragma unroll
        for (int nf = 0; nf < NF; ++nf) acc[zr][nf] = 0.f;
    const unsigned short* aBase = A + (row0 + m15) * Kp + q * 8;
    const unsigned short* wBase = Wb + m15 * Kp + q * 8;
    for (int ks = 0; ks < KS; ++ks) {
        v8s bz[ZR];
#pragma unroll
        for (int zr = 0; zr < ZR; ++zr)
            bz[zr] = *(const v8s*)(aBase + (size_t)zr * 16 * Kp + ks * 32);
#pragma unroll
        for (int nf = 0; nf < NF; ++nf) {
            v8s a = *(const v8s*)(wBase + (size_t)nf * 16 * Kp + ks * 32);
#pragma unroll
            for (int zr = 0; zr < ZR; ++zr)
                acc[zr][nf] = __builtin_amdgcn_mfma_f32_16x16x32_bf16(
                    a, bz[zr], acc[zr][nf], 0, 0, 0);
        }
    }
#pragma unroll
    for (int zr = 0; zr < ZR; ++zr) {
        const long m = row0 + zr * 16 + m15;
#pragma unroll
        for (int nf = 0; nf < NF; ++nf) {
            f32x4 b4 = *(const f32x4*)(bp + nf * 16 + q * 4);
            f32x4 c = acc[zr][nf];
            float v0 = fmaxf(c[0] + b4[0], 0.f), v1 = fmaxf(c[1] + b4[1], 0.f);
            float v2 = fmaxf(c[2] + b4[2], 0.f), v3 = fmaxf(c[3] + b4[3], 0.f);
            if (!FLAT) {
                ushort4 o; o.x = f2bf(v0); o.y = f2bf(v1); o.z = f2bf(v2); o.w = f2bf(v3);
                *(ushort4*)(Hout + (size_t)m * Np + nf * 16 + q * 4) = o;
            } else {
                const int n0 = nf * 16 + q * 4;
                if (n0 <= 48) {
                    const long s = m / 20; const int u = (int)(m - s * 20);
                    unsigned short* base = Hout + (size_t)s * 1024 + u * 50 + n0;
                    unsigned int lo = (unsigned int)f2bf(v0) | ((unsigned int)f2bf(v1) << 16);
                    *(unsigned int*)(base) = lo;
                    if (n0 < 48) {
                        unsigned int hi = (unsigned int)f2bf(v2) | ((unsigned int)f2bf(v3) << 16);
                        *(unsigned int*)(base + 2) = hi;
                    }
                }
            }
        }
    }
}

// logits = W5 h4 + b5; softmax -> out. h4 in g_bufA (112-padded rows).
__global__ __launch_bounds__(256)
void head_kernel(const float* __restrict__ W5, const float* __restrict__ b5,
                 float* __restrict__ out) {
    __shared__ float w5s[300];
    __shared__ float b5s[3];
    const int t = threadIdx.x;
    for (int i = t; i < 300; i += 256) w5s[i] = W5[i];
    if (t < 3) b5s[t] = b5[t];
    __syncthreads();
    const int s = blockIdx.x * 256 + t;
    const unsigned short* h = g_bufA + (size_t)s * 112;
    float a0 = b5s[0], a1 = b5s[1], a2 = b5s[2];
    for (int k = 0; k < 100; ++k) {
        float hv = bf2f(h[k]);
        a0 += hv * w5s[k]; a1 += hv * w5s[100 + k]; a2 += hv * w5s[200 + k];
    }
    float m = fmaxf(a0, fmaxf(a1, a2));
    float e0 = expf(a0 - m), e1 = expf(a1 - m), e2 = expf(a2 - m);
    float inv = 1.f / (e0 + e1 + e2);
    out[(size_t)s * 3 + 0] = e0 * inv;
    out[(size_t)s * 3 + 1] = e1 * inv;
    out[(size_t)s * 3 + 2] = e2 * inv;
}

extern "C" void kernel_launch(void* const* d_in, const int* in_sizes, int n_in,
                              void* d_out, int out_size, void* d_ws, size_t ws_size,
                              hipStream_t stream) {
    const float* x  = (const float*)d_in[0];
    const float* W1 = (const float*)d_in[1];
    const float* b1 = (const float*)d_in[2];
    const float* W2 = (const float*)d_in[3];
    const float* b2 = (const float*)d_in[4];
    const float* W3 = (const float*)d_in[5];
    const float* b3 = (const float*)d_in[6];
    const float* W4 = (const float*)d_in[7];
    const float* b4 = (const float*)d_in[8];
    const float* W5 = (const float*)d_in[9];
    const float* b5 = (const float*)d_in[10];
    float* out = (float*)d_out;

    zero_C_kernel<<<3, P * P, 0, stream>>>();
    prep_kernel<<<256, 256, 0, stream>>>(W1, b1, W2, b2, W3, b3, W4, b4);

    knn1_kernel<<<BB / SPB, NT, 0, stream>>>(x);
    agg_kernel<128, true, 0, 4><<<1024, 256, 0, stream>>>(x);        // x -> z1(A)
    gemm_kernel<128, 320, 2, false, 1, true><<<2560, 256, 0, stream>>>();   // z1 -> h1(B)

    knn_mfma_kernel<320, 1><<<BB / 16, NT, 0, stream>>>();           // h1 -> C1
    agg_kernel<320, false, 1, 2><<<1024, 256, 0, stream>>>(nullptr); // h1 -> z2(A)
    gemm_kernel<320, 128, 4, false, 2, true><<<1280, 256, 0, stream>>>();   // z2 -> h2(B)

    knn_mfma_kernel<128, 2><<<BB / 16, NT, 0, stream>>>();           // h2 -> C2
    agg_kernel<128, false, 2, 4><<<1024, 256, 0, stream>>>(nullptr); // h2 -> z3(A)
    gemm_kernel<128, 64, 4, true, 3, true><<<1280, 256, 0, stream>>>();     // z3 -> h3f(B)

    gemm_kernel<1024, 112, 1, false, 4, false><<<256, 256, 0, stream>>>();  // h3f -> h4(A)
    head_kernel<<<BB / 256, 256, 0, stream>>>(W5, b5, out);
}